// Round 4
// baseline (12151.473 us; speedup 1.0000x reference)
//
#include <hip/hip_runtime.h>
#include <stdint.h>

// LSTM layer with DropConnect, T=256 B=64 I=512 H=1024.
// out = [outputs(T,B,H) | hT(B,H) | cT(B,H)] f32.
//
// Round 4: round 3's fp32-equivalent split-fp16 math kept, but workspace cut
// 395MB -> 126MB (round-3 crash = ws overflow; rounds 1-2 proved ~198MB ok):
//   - xp (268MB) ELIMINATED: input projection computed on the fly in lstm_rec
//     (K=512, 3-MFMA split per k-frag, x read pre-wait so latency overlaps)
//   - W_ih fragment-packed per WG (prep2b) and LDS-resident like Wh
// Math: x = hi + lo/2048 (both fp16); A.B = AhBh + (AhBl+AlBh)/2048.
// W_hh pre-scaled x32, W_ih x16 (hi stays fp16-normal).
// Sync/write structure identical to rounds 1-2 (validated outputs+hT).

#define T_STEPS 256
#define HSLOT   65600                 // 65536 + 64 pad elems per h plane slot

// workspace byte offsets (total 126,435,584 B ~ 121 MiB)
#define ABFH_OFF   0u                 // 16384*512 fp16 = 16777216
#define ABFL_OFF   16777216u          // 16777216
#define WIHFH_OFF  33554432u          // 256*16*64*8 fp16 = 4194304
#define WIHFL_OFF  37748736u          // 4194304
#define WHFH_OFF   41943040u          // 256*32*64*8 fp16 = 8388608
#define WHFL_OFF   50331648u          // 8388608
#define BSUM_OFF   58720256u          // 4096 f32 = 16384
#define FLAGS_OFF  58736640u          // 256*256 u32 = 262144
#define HHH_OFF    58998784u          // 257*HSLOT fp16 = 33718400
#define HHL_OFF    92717184u          // 33718400

typedef __attribute__((ext_vector_type(4))) float f32x4;
typedef __attribute__((ext_vector_type(4))) unsigned int u32x4;

__device__ __forceinline__ void split16(float x, unsigned short& hi, unsigned short& lo) {
  _Float16 h = (_Float16)x;
  float r = (x - (float)h) * 2048.0f;
  _Float16 l = (_Float16)r;
  hi = __builtin_bit_cast(unsigned short, h);
  lo = __builtin_bit_cast(unsigned short, l);
}
__device__ __forceinline__ float sigmoidf_(float x) {
  return 1.0f / (1.0f + __expf(-x));
}

// D = A*B + C, 16x16x32 fp16, raw-bits operands.
__device__ __forceinline__ f32x4 mfma16(u32x4 a, u32x4 b, f32x4 c) {
  asm("v_mfma_f32_16x16x32_f16 %0, %1, %2, %0" : "+v"(c) : "v"(a), "v"(b));
  return c;
}

// ---------------- prep1: input/h0 splits + bias sum + flag zeroing ----------------
__global__ void prep1(const float* __restrict__ input, const float* __restrict__ bih,
                      const float* __restrict__ bhh, const float* __restrict__ h0,
                      unsigned short* __restrict__ abfh, unsigned short* __restrict__ abfl,
                      float* __restrict__ bsum, unsigned int* __restrict__ flags,
                      unsigned short* __restrict__ hhh, unsigned short* __restrict__ hhl) {
  int gid = blockIdx.x * blockDim.x + threadIdx.x;
  int stride = gridDim.x * blockDim.x;
  // input (unscaled): 2097152 float4
  for (int i = gid; i < 2097152; i += stride) {
    float4 v = reinterpret_cast<const float4*>(input)[i];
    ushort4 h, l;
    split16(v.x, h.x, l.x); split16(v.y, h.y, l.y);
    split16(v.z, h.z, l.z); split16(v.w, h.w, l.w);
    reinterpret_cast<ushort4*>(abfh)[i] = h;
    reinterpret_cast<ushort4*>(abfl)[i] = l;
  }
  // h0 -> h_hist slot 0 (hi+lo planes)
  for (int i = gid; i < 16384; i += stride) {
    float4 v = reinterpret_cast<const float4*>(h0)[i];
    ushort4 h, l;
    split16(v.x, h.x, l.x); split16(v.y, h.y, l.y);
    split16(v.z, h.z, l.z); split16(v.w, h.w, l.w);
    reinterpret_cast<ushort4*>(hhh)[i] = h;
    reinterpret_cast<ushort4*>(hhl)[i] = l;
  }
  for (int i = gid; i < 4096; i += stride) bsum[i] = bih[i] + bhh[i];
  for (int i = gid; i < 65536; i += stride) flags[i] = 0u;
}

// ------- prep2: Wh = (W_hh*mask)^T * 32, packed in per-WG MFMA B-frag order -------
// item idx = (wg*32 + s)*64 + lane ; 8 fp16 per item (per plane).
// lane: cc=lane&15 -> gate col = (cc>>2)*1024 + wg*4 + (cc&3); k = s*32+(lane>>4)*8+j
__global__ void prep2(const float* __restrict__ whh, const float* __restrict__ wmask,
                      unsigned short* __restrict__ whfh, unsigned short* __restrict__ whfl) {
  int idx = blockIdx.x * 256 + threadIdx.x;   // 524288 total
  int lane = idx & 63;
  int s = (idx >> 6) & 31;
  int wg = idx >> 11;
  int cc = lane & 15;
  int n = (cc >> 2) * 1024 + wg * 4 + (cc & 3);
  int k0 = s * 32 + (lane >> 4) * 8;
  const float4* s4 = reinterpret_cast<const float4*>(whh + (size_t)n * 1024 + k0);
  const float4* m4 = reinterpret_cast<const float4*>(wmask + (size_t)n * 1024 + k0);
  float4 a = s4[0], b = s4[1], ma = m4[0], mb = m4[1];
  ushort4 h0_, h1_, l0_, l1_;
  split16(a.x * ma.x * 32.f, h0_.x, l0_.x); split16(a.y * ma.y * 32.f, h0_.y, l0_.y);
  split16(a.z * ma.z * 32.f, h0_.z, l0_.z); split16(a.w * ma.w * 32.f, h0_.w, l0_.w);
  split16(b.x * mb.x * 32.f, h1_.x, l1_.x); split16(b.y * mb.y * 32.f, h1_.y, l1_.y);
  split16(b.z * mb.z * 32.f, h1_.z, l1_.z); split16(b.w * mb.w * 32.f, h1_.w, l1_.w);
  reinterpret_cast<ushort4*>(whfh)[idx * 2]     = h0_;
  reinterpret_cast<ushort4*>(whfh)[idx * 2 + 1] = h1_;
  reinterpret_cast<ushort4*>(whfl)[idx * 2]     = l0_;
  reinterpret_cast<ushort4*>(whfl)[idx * 2 + 1] = l1_;
}

// ------- prep2b: W_ih^T * 16, packed in per-WG MFMA B-frag order (K=512) -------
// item idx = (wg*16 + s)*64 + lane ; same lane->(col,k) map as prep2.
__global__ void prep2b(const float* __restrict__ wih,
                       unsigned short* __restrict__ wihfh, unsigned short* __restrict__ wihfl) {
  int idx = blockIdx.x * 256 + threadIdx.x;   // 262144 total
  int lane = idx & 63;
  int s = (idx >> 6) & 15;
  int wg = idx >> 10;
  int cc = lane & 15;
  int n = (cc >> 2) * 1024 + wg * 4 + (cc & 3);
  int k0 = s * 32 + (lane >> 4) * 8;
  const float4* s4 = reinterpret_cast<const float4*>(wih + (size_t)n * 512 + k0);
  float4 a = s4[0], b = s4[1];
  ushort4 h0_, h1_, l0_, l1_;
  split16(a.x * 16.f, h0_.x, l0_.x); split16(a.y * 16.f, h0_.y, l0_.y);
  split16(a.z * 16.f, h0_.z, l0_.z); split16(a.w * 16.f, h0_.w, l0_.w);
  split16(b.x * 16.f, h1_.x, l1_.x); split16(b.y * 16.f, h1_.y, l1_.y);
  split16(b.z * 16.f, h1_.z, l1_.z); split16(b.w * 16.f, h1_.w, l1_.w);
  reinterpret_cast<ushort4*>(wihfh)[idx * 2]     = h0_;
  reinterpret_cast<ushort4*>(wihfh)[idx * 2 + 1] = h1_;
  reinterpret_cast<ushort4*>(wihfl)[idx * 2]     = l0_;
  reinterpret_cast<ushort4*>(wihfl)[idx * 2 + 1] = l1_;
}

// ---------------- lstm_rec: persistent recurrence ----------------
// 256 WGs x 256 thr. WG wg owns h cols [wg*4,wg*4+4), gate cols {c*1024+wg*4+j}.
// Wh and W_ih hi+lo fragment-ordered in LDS (96KB). Per step:
//   accI (x_t @ W_ih, pre-wait, no dependency) ; wait flag ; accH (h @ Wh) ;
//   gg = accH/32 + accHL/65536 + accI/16 + accIL/32768 + bias ; cell; write; flag.
__global__ void __launch_bounds__(256, 1)
lstm_rec(const unsigned short* __restrict__ whfh, const unsigned short* __restrict__ whfl,
         const unsigned short* __restrict__ wihfh, const unsigned short* __restrict__ wihfl,
         const unsigned short* __restrict__ abfh, const unsigned short* __restrict__ abfl,
         const float* __restrict__ c0,            // [64][1024]
         const float* __restrict__ bsum,          // [4096]
         unsigned short* __restrict__ hhh,        // 257 slots hi plane
         unsigned short* __restrict__ hhl,        // 257 slots lo plane
         unsigned int* __restrict__ flags,        // [256][256]
         float* __restrict__ out) {
  __shared__ unsigned short lWhh[32 * 64 * 8];    // 32KB
  __shared__ unsigned short lWhl[32 * 64 * 8];    // 32KB
  __shared__ unsigned short lIhh[16 * 64 * 8];    // 16KB
  __shared__ unsigned short lIhl[16 * 64 * 8];    // 16KB
  const int tid = threadIdx.x;
  const int wg = blockIdx.x;
  const int w = tid >> 6, l = tid & 63;
  const int g = l >> 4, cc = l & 15, jj = l & 3, chunk = cc >> 2;

  {
    const u32x4* srch = reinterpret_cast<const u32x4*>(whfh) + (size_t)wg * 2048;
    const u32x4* srcl = reinterpret_cast<const u32x4*>(whfl) + (size_t)wg * 2048;
    u32x4* dsth = reinterpret_cast<u32x4*>(lWhh);
    u32x4* dstl = reinterpret_cast<u32x4*>(lWhl);
    for (int i = tid; i < 2048; i += 256) { dsth[i] = srch[i]; dstl[i] = srcl[i]; }
    const u32x4* sih = reinterpret_cast<const u32x4*>(wihfh) + (size_t)wg * 1024;
    const u32x4* sil = reinterpret_cast<const u32x4*>(wihfl) + (size_t)wg * 1024;
    u32x4* dih = reinterpret_cast<u32x4*>(lIhh);
    u32x4* dil = reinterpret_cast<u32x4*>(lIhl);
    for (int i = tid; i < 1024; i += 256) { dih[i] = sih[i]; dil[i] = sil[i]; }
  }
  const int hcol = wg * 4 + jj;
  float c_st[4];
  #pragma unroll
  for (int q = 0; q < 4; q++) c_st[q] = c0[(size_t)(16 * w + 4 * g + q) * 1024 + hcol];
  const int gcol = chunk * 1024 + wg * 4 + jj;
  const float bs = bsum[gcol];
  const int arow = 16 * w + cc;
  __syncthreads();

  const u32x4* lbh = reinterpret_cast<const u32x4*>(lWhh);
  const u32x4* lbl = reinterpret_cast<const u32x4*>(lWhl);
  const u32x4* lih = reinterpret_cast<const u32x4*>(lIhh);
  const u32x4* lil = reinterpret_cast<const u32x4*>(lIhl);

  for (int t = 0; t < T_STEPS; t++) {
    // ---- input projection for step t (no flag dependency: issue pre-wait) ----
    f32x4 accI0 = {0.f, 0.f, 0.f, 0.f}, accI1 = {0.f, 0.f, 0.f, 0.f};
    f32x4 accIL = {0.f, 0.f, 0.f, 0.f};
    {
      const unsigned short* xrh = abfh + ((size_t)(t * 64 + arow)) * 512;
      const unsigned short* xrl = abfl + ((size_t)(t * 64 + arow)) * 512;
      #pragma unroll
      for (int s = 0; s < 8; s++) {
        u32x4 a0h = *reinterpret_cast<const u32x4*>(xrh + s * 32 + g * 8);
        u32x4 a0l = *reinterpret_cast<const u32x4*>(xrl + s * 32 + g * 8);
        u32x4 b0h = lih[s * 64 + l], b0l = lil[s * 64 + l];
        accI0 = mfma16(a0h, b0h, accI0);
        accIL = mfma16(a0h, b0l, accIL);
        accIL = mfma16(a0l, b0h, accIL);
        u32x4 a1h = *reinterpret_cast<const u32x4*>(xrh + (s + 8) * 32 + g * 8);
        u32x4 a1l = *reinterpret_cast<const u32x4*>(xrl + (s + 8) * 32 + g * 8);
        u32x4 b1h = lih[(s + 8) * 64 + l], b1l = lil[(s + 8) * 64 + l];
        accI1 = mfma16(a1h, b1h, accI1);
        accIL = mfma16(a1h, b1l, accIL);
        accIL = mfma16(a1l, b1h, accIL);
      }
    }
    // ---- wait for all WGs to have published h[t] ----
    unsigned int fv = 0;
    if (t > 0) {
      const unsigned int* f = flags + (size_t)(t - 1) * 256 + tid;
      do {
        fv = __hip_atomic_load(f, __ATOMIC_RELAXED, __HIP_MEMORY_SCOPE_AGENT);
        if (!fv) __builtin_amdgcn_s_sleep(1);
      } while (!fv);
      __syncthreads();
    }
    // ---- h @ Wh (fv>>31 == 0: data-dependency fence vs hoisting) ----
    const unsigned short* hrh = hhh + (size_t)t * HSLOT + (size_t)arow * 1024 + (fv >> 31);
    const unsigned short* hrl = hhl + (size_t)t * HSLOT + (size_t)arow * 1024 + (fv >> 31);
    f32x4 acc0 = {0.f, 0.f, 0.f, 0.f}, acc1 = {0.f, 0.f, 0.f, 0.f};
    f32x4 accL0 = {0.f, 0.f, 0.f, 0.f}, accL1 = {0.f, 0.f, 0.f, 0.f};
    #pragma unroll
    for (int s = 0; s < 16; s++) {
      u32x4 a0h = *reinterpret_cast<const u32x4*>(hrh + s * 32 + g * 8);
      u32x4 a0l = *reinterpret_cast<const u32x4*>(hrl + s * 32 + g * 8);
      u32x4 b0h = lbh[s * 64 + l], b0l = lbl[s * 64 + l];
      acc0  = mfma16(a0h, b0h, acc0);
      accL0 = mfma16(a0h, b0l, accL0);
      accL0 = mfma16(a0l, b0h, accL0);
      u32x4 a1h = *reinterpret_cast<const u32x4*>(hrh + (s + 16) * 32 + g * 8);
      u32x4 a1l = *reinterpret_cast<const u32x4*>(hrl + (s + 16) * 32 + g * 8);
      u32x4 b1h = lbh[(s + 16) * 64 + l], b1l = lbl[(s + 16) * 64 + l];
      acc1  = mfma16(a1h, b1h, acc1);
      accL1 = mfma16(a1h, b1l, accL1);
      accL1 = mfma16(a1l, b1h, accL1);
    }
    // ---- cell update ----
    float hq[4];
    #pragma unroll
    for (int q = 0; q < 4; q++) {
      float gg = (acc0[q] + acc1[q]) * 0.03125f
               + (accL0[q] + accL1[q]) * (1.f / 65536.f)
               + (accI0[q] + accI1[q]) * 0.0625f
               + accIL[q] * (1.f / 32768.f) + bs;
      int base = l & 51;                  // keep jj (bits 0-1) and g (bits 4-5)
      float vi = __shfl(gg, base | 0, 64);
      float vf = __shfl(gg, base | 4, 64);
      float vg = __shfl(gg, base | 8, 64);
      float vo = __shfl(gg, base | 12, 64);
      float ii = sigmoidf_(vi), ff = sigmoidf_(vf);
      float gz = tanhf(vg), oo = sigmoidf_(vo);
      float cn = ff * c_st[q] + ii * gz;
      c_st[q] = cn;
      hq[q] = oo * tanhf(cn);
    }
    // ---- role-split writes (all chunks hold identical hq/c) ----
    const int orow = 16 * w + 4 * g;
    if (chunk == 0) {                     // h hi plane
      unsigned short* hd = hhh + (size_t)(t + 1) * HSLOT + (size_t)orow * 1024 + hcol;
      #pragma unroll
      for (int q = 0; q < 4; q++) {
        unsigned short hi, lo; split16(hq[q], hi, lo);
        __builtin_nontemporal_store(hi, hd + (size_t)q * 1024);
      }
    } else if (chunk == 2) {              // h lo plane (+ hT at last step)
      unsigned short* hd = hhl + (size_t)(t + 1) * HSLOT + (size_t)orow * 1024 + hcol;
      #pragma unroll
      for (int q = 0; q < 4; q++) {
        unsigned short hi, lo; split16(hq[q], hi, lo);
        __builtin_nontemporal_store(lo, hd + (size_t)q * 1024);
      }
      if (t == T_STEPS - 1) {
        #pragma unroll
        for (int q = 0; q < 4; q++)
          out[16777216 + (size_t)(orow + q) * 1024 + hcol] = hq[q];
      }
    } else if (chunk == 1) {              // outputs
      float* od = out + (size_t)t * 65536 + (size_t)orow * 1024 + hcol;
      #pragma unroll
      for (int q = 0; q < 4; q++)
        __builtin_nontemporal_store(hq[q], od + (size_t)q * 1024);
    } else {                              // cT
      if (t == T_STEPS - 1) {
        #pragma unroll
        for (int q = 0; q < 4; q++)
          out[16842752 + (size_t)(orow + q) * 1024 + hcol] = c_st[q];
      }
    }
    __threadfence();
    __syncthreads();
    if (tid == 0)
      __hip_atomic_store(flags + (size_t)t * 256 + wg, 1u,
                         __ATOMIC_RELEASE, __HIP_MEMORY_SCOPE_AGENT);
  }
}

extern "C" void kernel_launch(void* const* d_in, const int* in_sizes, int n_in,
                              void* d_out, int out_size, void* d_ws, size_t ws_size,
                              hipStream_t stream) {
  const float* input = (const float*)d_in[0];
  const float* h0    = (const float*)d_in[1];
  const float* c0    = (const float*)d_in[2];
  const float* wmask = (const float*)d_in[3];
  const float* wih   = (const float*)d_in[4];
  const float* whh   = (const float*)d_in[5];
  const float* bih   = (const float*)d_in[6];
  const float* bhh   = (const float*)d_in[7];
  float* out = (float*)d_out;
  char* ws = (char*)d_ws;

  unsigned short* abfh  = (unsigned short*)(ws + ABFH_OFF);
  unsigned short* abfl  = (unsigned short*)(ws + ABFL_OFF);
  unsigned short* wihfh = (unsigned short*)(ws + WIHFH_OFF);
  unsigned short* wihfl = (unsigned short*)(ws + WIHFL_OFF);
  unsigned short* whfh  = (unsigned short*)(ws + WHFH_OFF);
  unsigned short* whfl  = (unsigned short*)(ws + WHFL_OFF);
  float*          bsum  = (float*)(ws + BSUM_OFF);
  unsigned int*   flags = (unsigned int*)(ws + FLAGS_OFF);
  unsigned short* hhh   = (unsigned short*)(ws + HHH_OFF);
  unsigned short* hhl   = (unsigned short*)(ws + HHL_OFF);

  hipLaunchKernelGGL(prep1, dim3(1024), dim3(256), 0, stream,
                     input, bih, bhh, h0, abfh, abfl, bsum, flags, hhh, hhl);
  hipLaunchKernelGGL(prep2, dim3(2048), dim3(256), 0, stream, whh, wmask, whfh, whfl);
  hipLaunchKernelGGL(prep2b, dim3(1024), dim3(256), 0, stream, wih, wihfh, wihfl);
  hipLaunchKernelGGL(lstm_rec, dim3(256), dim3(256), 0, stream,
                     whfh, whfl, wihfh, wihfl, abfh, abfl, c0, bsum, hhh, hhl, flags, out);
}

// Round 5
// 3976.527 us; speedup vs baseline: 3.0558x; 3.0558x over previous
//
#include <hip/hip_runtime.h>
#include <stdint.h>

// LSTM layer with DropConnect, T=256 B=64 I=512 H=1024.
// out = [outputs(T,B,H) | hT(B,H) | cT(B,H)] f32.
//
// Round 5: round 4 (PASS, absmax 0.031, lstm_rec 12.2ms) minus the per-step
// L2 writeback storm. Round 4 used __threadfence()+RELEASE flag: each emits
// buffer_wbl2/inv (full 4MiB L2 tag-walk) per WG per step -> ~47us/step with
// MfmaUtil 2%. New protocol: h stores are RELAXED+AGENT atomics (write-through
// sc0 sc1, no L2 dirty), s_waitcnt vmcnt(0) + barrier, then RELAXED flag
// publish. Consumer h loads stay plain: h slots are t-indexed first-touch so
// no stale L2 line can exist (kernel-begin invalidate covers graph replays).
// outputs/hT/cT stores moved after the flag (off critical path).
// Math/layout identical to round 4.

#define T_STEPS 256
#define HSLOT   65600                 // 65536 + 64 pad elems per h plane slot

// workspace byte offsets (total 126,435,584 B ~ 121 MiB)
#define ABFH_OFF   0u                 // 16384*512 fp16 = 16777216
#define ABFL_OFF   16777216u          // 16777216
#define WIHFH_OFF  33554432u          // 256*16*64*8 fp16 = 4194304
#define WIHFL_OFF  37748736u          // 4194304
#define WHFH_OFF   41943040u          // 256*32*64*8 fp16 = 8388608
#define WHFL_OFF   50331648u          // 8388608
#define BSUM_OFF   58720256u          // 4096 f32 = 16384
#define FLAGS_OFF  58736640u          // 256*256 u32 = 262144
#define HHH_OFF    58998784u          // 257*HSLOT fp16 = 33718400
#define HHL_OFF    92717184u          // 33718400

typedef __attribute__((ext_vector_type(4))) float f32x4;
typedef __attribute__((ext_vector_type(4))) unsigned int u32x4;

__device__ __forceinline__ void split16(float x, unsigned short& hi, unsigned short& lo) {
  _Float16 h = (_Float16)x;
  float r = (x - (float)h) * 2048.0f;
  _Float16 l = (_Float16)r;
  hi = __builtin_bit_cast(unsigned short, h);
  lo = __builtin_bit_cast(unsigned short, l);
}
__device__ __forceinline__ float sigmoidf_(float x) {
  return 1.0f / (1.0f + __expf(-x));
}

// D = A*B + C, 16x16x32 fp16, raw-bits operands.
__device__ __forceinline__ f32x4 mfma16(u32x4 a, u32x4 b, f32x4 c) {
  asm("v_mfma_f32_16x16x32_f16 %0, %1, %2, %0" : "+v"(c) : "v"(a), "v"(b));
  return c;
}

// write-through u16 store (agent-visible once vmcnt retires; no L2 dirty line)
__device__ __forceinline__ void st16_wt(unsigned short* p, unsigned short v) {
  __hip_atomic_store(p, v, __ATOMIC_RELAXED, __HIP_MEMORY_SCOPE_AGENT);
}

// ---------------- prep1: input/h0 splits + bias sum + flag zeroing ----------------
__global__ void prep1(const float* __restrict__ input, const float* __restrict__ bih,
                      const float* __restrict__ bhh, const float* __restrict__ h0,
                      unsigned short* __restrict__ abfh, unsigned short* __restrict__ abfl,
                      float* __restrict__ bsum, unsigned int* __restrict__ flags,
                      unsigned short* __restrict__ hhh, unsigned short* __restrict__ hhl) {
  int gid = blockIdx.x * blockDim.x + threadIdx.x;
  int stride = gridDim.x * blockDim.x;
  // input (unscaled): 2097152 float4
  for (int i = gid; i < 2097152; i += stride) {
    float4 v = reinterpret_cast<const float4*>(input)[i];
    ushort4 h, l;
    split16(v.x, h.x, l.x); split16(v.y, h.y, l.y);
    split16(v.z, h.z, l.z); split16(v.w, h.w, l.w);
    reinterpret_cast<ushort4*>(abfh)[i] = h;
    reinterpret_cast<ushort4*>(abfl)[i] = l;
  }
  // h0 -> h_hist slot 0 (hi+lo planes)
  for (int i = gid; i < 16384; i += stride) {
    float4 v = reinterpret_cast<const float4*>(h0)[i];
    ushort4 h, l;
    split16(v.x, h.x, l.x); split16(v.y, h.y, l.y);
    split16(v.z, h.z, l.z); split16(v.w, h.w, l.w);
    reinterpret_cast<ushort4*>(hhh)[i] = h;
    reinterpret_cast<ushort4*>(hhl)[i] = l;
  }
  for (int i = gid; i < 4096; i += stride) bsum[i] = bih[i] + bhh[i];
  for (int i = gid; i < 65536; i += stride) flags[i] = 0u;
}

// ------- prep2: Wh = (W_hh*mask)^T * 32, packed in per-WG MFMA B-frag order -------
// item idx = (wg*32 + s)*64 + lane ; 8 fp16 per item (per plane).
// lane: cc=lane&15 -> gate col = (cc>>2)*1024 + wg*4 + (cc&3); k = s*32+(lane>>4)*8+j
__global__ void prep2(const float* __restrict__ whh, const float* __restrict__ wmask,
                      unsigned short* __restrict__ whfh, unsigned short* __restrict__ whfl) {
  int idx = blockIdx.x * 256 + threadIdx.x;   // 524288 total
  int lane = idx & 63;
  int s = (idx >> 6) & 31;
  int wg = idx >> 11;
  int cc = lane & 15;
  int n = (cc >> 2) * 1024 + wg * 4 + (cc & 3);
  int k0 = s * 32 + (lane >> 4) * 8;
  const float4* s4 = reinterpret_cast<const float4*>(whh + (size_t)n * 1024 + k0);
  const float4* m4 = reinterpret_cast<const float4*>(wmask + (size_t)n * 1024 + k0);
  float4 a = s4[0], b = s4[1], ma = m4[0], mb = m4[1];
  ushort4 h0_, h1_, l0_, l1_;
  split16(a.x * ma.x * 32.f, h0_.x, l0_.x); split16(a.y * ma.y * 32.f, h0_.y, l0_.y);
  split16(a.z * ma.z * 32.f, h0_.z, l0_.z); split16(a.w * ma.w * 32.f, h0_.w, l0_.w);
  split16(b.x * mb.x * 32.f, h1_.x, l1_.x); split16(b.y * mb.y * 32.f, h1_.y, l1_.y);
  split16(b.z * mb.z * 32.f, h1_.z, l1_.z); split16(b.w * mb.w * 32.f, h1_.w, l1_.w);
  reinterpret_cast<ushort4*>(whfh)[idx * 2]     = h0_;
  reinterpret_cast<ushort4*>(whfh)[idx * 2 + 1] = h1_;
  reinterpret_cast<ushort4*>(whfl)[idx * 2]     = l0_;
  reinterpret_cast<ushort4*>(whfl)[idx * 2 + 1] = l1_;
}

// ------- prep2b: W_ih^T * 16, packed in per-WG MFMA B-frag order (K=512) -------
// item idx = (wg*16 + s)*64 + lane ; same lane->(col,k) map as prep2.
__global__ void prep2b(const float* __restrict__ wih,
                       unsigned short* __restrict__ wihfh, unsigned short* __restrict__ wihfl) {
  int idx = blockIdx.x * 256 + threadIdx.x;   // 262144 total
  int lane = idx & 63;
  int s = (idx >> 6) & 15;
  int wg = idx >> 10;
  int cc = lane & 15;
  int n = (cc >> 2) * 1024 + wg * 4 + (cc & 3);
  int k0 = s * 32 + (lane >> 4) * 8;
  const float4* s4 = reinterpret_cast<const float4*>(wih + (size_t)n * 512 + k0);
  float4 a = s4[0], b = s4[1];
  ushort4 h0_, h1_, l0_, l1_;
  split16(a.x * 16.f, h0_.x, l0_.x); split16(a.y * 16.f, h0_.y, l0_.y);
  split16(a.z * 16.f, h0_.z, l0_.z); split16(a.w * 16.f, h0_.w, l0_.w);
  split16(b.x * 16.f, h1_.x, l1_.x); split16(b.y * 16.f, h1_.y, l1_.y);
  split16(b.z * 16.f, h1_.z, l1_.z); split16(b.w * 16.f, h1_.w, l1_.w);
  reinterpret_cast<ushort4*>(wihfh)[idx * 2]     = h0_;
  reinterpret_cast<ushort4*>(wihfh)[idx * 2 + 1] = h1_;
  reinterpret_cast<ushort4*>(wihfl)[idx * 2]     = l0_;
  reinterpret_cast<ushort4*>(wihfl)[idx * 2 + 1] = l1_;
}

// ---------------- lstm_rec: persistent recurrence ----------------
// 256 WGs x 256 thr. WG wg owns h cols [wg*4,wg*4+4), gate cols {c*1024+wg*4+j}.
// Wh and W_ih hi+lo fragment-ordered in LDS (96KB). Per step:
//   accI (x_t @ W_ih, pre-wait) ; poll flags ; accH (h @ Wh) ; cell ;
//   h wt-stores ; vmcnt(0) ; barrier ; flag publish ; outputs (post-flag).
__global__ void __launch_bounds__(256, 1)
lstm_rec(const unsigned short* __restrict__ whfh, const unsigned short* __restrict__ whfl,
         const unsigned short* __restrict__ wihfh, const unsigned short* __restrict__ wihfl,
         const unsigned short* __restrict__ abfh, const unsigned short* __restrict__ abfl,
         const float* __restrict__ c0,            // [64][1024]
         const float* __restrict__ bsum,          // [4096]
         unsigned short* __restrict__ hhh,        // 257 slots hi plane
         unsigned short* __restrict__ hhl,        // 257 slots lo plane
         unsigned int* __restrict__ flags,        // [256][256]
         float* __restrict__ out) {
  __shared__ unsigned short lWhh[32 * 64 * 8];    // 32KB
  __shared__ unsigned short lWhl[32 * 64 * 8];    // 32KB
  __shared__ unsigned short lIhh[16 * 64 * 8];    // 16KB
  __shared__ unsigned short lIhl[16 * 64 * 8];    // 16KB
  const int tid = threadIdx.x;
  const int wg = blockIdx.x;
  const int w = tid >> 6, l = tid & 63;
  const int g = l >> 4, cc = l & 15, jj = l & 3, chunk = cc >> 2;

  {
    const u32x4* srch = reinterpret_cast<const u32x4*>(whfh) + (size_t)wg * 2048;
    const u32x4* srcl = reinterpret_cast<const u32x4*>(whfl) + (size_t)wg * 2048;
    u32x4* dsth = reinterpret_cast<u32x4*>(lWhh);
    u32x4* dstl = reinterpret_cast<u32x4*>(lWhl);
    for (int i = tid; i < 2048; i += 256) { dsth[i] = srch[i]; dstl[i] = srcl[i]; }
    const u32x4* sih = reinterpret_cast<const u32x4*>(wihfh) + (size_t)wg * 1024;
    const u32x4* sil = reinterpret_cast<const u32x4*>(wihfl) + (size_t)wg * 1024;
    u32x4* dih = reinterpret_cast<u32x4*>(lIhh);
    u32x4* dil = reinterpret_cast<u32x4*>(lIhl);
    for (int i = tid; i < 1024; i += 256) { dih[i] = sih[i]; dil[i] = sil[i]; }
  }
  const int hcol = wg * 4 + jj;
  float c_st[4];
  #pragma unroll
  for (int q = 0; q < 4; q++) c_st[q] = c0[(size_t)(16 * w + 4 * g + q) * 1024 + hcol];
  const int gcol = chunk * 1024 + wg * 4 + jj;
  const float bs = bsum[gcol];
  const int arow = 16 * w + cc;
  __syncthreads();

  const u32x4* lbh = reinterpret_cast<const u32x4*>(lWhh);
  const u32x4* lbl = reinterpret_cast<const u32x4*>(lWhl);
  const u32x4* lih = reinterpret_cast<const u32x4*>(lIhh);
  const u32x4* lil = reinterpret_cast<const u32x4*>(lIhl);

  for (int t = 0; t < T_STEPS; t++) {
    // ---- input projection for step t (no flag dependency: issue pre-wait) ----
    f32x4 accI0 = {0.f, 0.f, 0.f, 0.f}, accI1 = {0.f, 0.f, 0.f, 0.f};
    f32x4 accIL = {0.f, 0.f, 0.f, 0.f};
    {
      const unsigned short* xrh = abfh + ((size_t)(t * 64 + arow)) * 512;
      const unsigned short* xrl = abfl + ((size_t)(t * 64 + arow)) * 512;
      #pragma unroll
      for (int s = 0; s < 8; s++) {
        u32x4 a0h = *reinterpret_cast<const u32x4*>(xrh + s * 32 + g * 8);
        u32x4 a0l = *reinterpret_cast<const u32x4*>(xrl + s * 32 + g * 8);
        u32x4 b0h = lih[s * 64 + l], b0l = lil[s * 64 + l];
        accI0 = mfma16(a0h, b0h, accI0);
        accIL = mfma16(a0h, b0l, accIL);
        accIL = mfma16(a0l, b0h, accIL);
        u32x4 a1h = *reinterpret_cast<const u32x4*>(xrh + (s + 8) * 32 + g * 8);
        u32x4 a1l = *reinterpret_cast<const u32x4*>(xrl + (s + 8) * 32 + g * 8);
        u32x4 b1h = lih[(s + 8) * 64 + l], b1l = lil[(s + 8) * 64 + l];
        accI1 = mfma16(a1h, b1h, accI1);
        accIL = mfma16(a1h, b1l, accIL);
        accIL = mfma16(a1l, b1h, accIL);
      }
    }
    // ---- wait for all WGs to have published h[t] ----
    unsigned int fv = 0;
    if (t > 0) {
      const unsigned int* f = flags + (size_t)(t - 1) * 256 + tid;
      do {
        fv = __hip_atomic_load(f, __ATOMIC_RELAXED, __HIP_MEMORY_SCOPE_AGENT);
        if (!fv) __builtin_amdgcn_s_sleep(1);
      } while (!fv);
      __syncthreads();
    }
    // ---- h @ Wh (fv>>31 == 0: data-dependency fence vs hoisting) ----
    const unsigned short* hrh = hhh + (size_t)t * HSLOT + (size_t)arow * 1024 + (fv >> 31);
    const unsigned short* hrl = hhl + (size_t)t * HSLOT + (size_t)arow * 1024 + (fv >> 31);
    f32x4 acc0 = {0.f, 0.f, 0.f, 0.f}, acc1 = {0.f, 0.f, 0.f, 0.f};
    f32x4 accL0 = {0.f, 0.f, 0.f, 0.f}, accL1 = {0.f, 0.f, 0.f, 0.f};
    #pragma unroll
    for (int s = 0; s < 16; s++) {
      u32x4 a0h = *reinterpret_cast<const u32x4*>(hrh + s * 32 + g * 8);
      u32x4 a0l = *reinterpret_cast<const u32x4*>(hrl + s * 32 + g * 8);
      u32x4 b0h = lbh[s * 64 + l], b0l = lbl[s * 64 + l];
      acc0  = mfma16(a0h, b0h, acc0);
      accL0 = mfma16(a0h, b0l, accL0);
      accL0 = mfma16(a0l, b0h, accL0);
      u32x4 a1h = *reinterpret_cast<const u32x4*>(hrh + (s + 16) * 32 + g * 8);
      u32x4 a1l = *reinterpret_cast<const u32x4*>(hrl + (s + 16) * 32 + g * 8);
      u32x4 b1h = lbh[(s + 16) * 64 + l], b1l = lbl[(s + 16) * 64 + l];
      acc1  = mfma16(a1h, b1h, acc1);
      accL1 = mfma16(a1h, b1l, accL1);
      accL1 = mfma16(a1l, b1h, accL1);
    }
    // ---- cell update ----
    float hq[4];
    #pragma unroll
    for (int q = 0; q < 4; q++) {
      float gg = (acc0[q] + acc1[q]) * 0.03125f
               + (accL0[q] + accL1[q]) * (1.f / 65536.f)
               + (accI0[q] + accI1[q]) * 0.0625f
               + accIL[q] * (1.f / 32768.f) + bs;
      int base = l & 51;                  // keep jj (bits 0-1) and g (bits 4-5)
      float vi = __shfl(gg, base | 0, 64);
      float vf = __shfl(gg, base | 4, 64);
      float vg = __shfl(gg, base | 8, 64);
      float vo = __shfl(gg, base | 12, 64);
      float ii = sigmoidf_(vi), ff = sigmoidf_(vf);
      float gz = tanhf(vg), oo = sigmoidf_(vo);
      float cn = ff * c_st[q] + ii * gz;
      c_st[q] = cn;
      hq[q] = oo * tanhf(cn);
    }
    // ---- h-plane write-through stores (critical path) ----
    const int orow = 16 * w + 4 * g;
    if (chunk == 0) {                     // h hi plane
      unsigned short* hd = hhh + (size_t)(t + 1) * HSLOT + (size_t)orow * 1024 + hcol;
      #pragma unroll
      for (int q = 0; q < 4; q++) {
        unsigned short hi, lo; split16(hq[q], hi, lo);
        st16_wt(hd + (size_t)q * 1024, hi);
      }
    } else if (chunk == 2) {              // h lo plane
      unsigned short* hd = hhl + (size_t)(t + 1) * HSLOT + (size_t)orow * 1024 + hcol;
      #pragma unroll
      for (int q = 0; q < 4; q++) {
        unsigned short hi, lo; split16(hq[q], hi, lo);
        st16_wt(hd + (size_t)q * 1024, lo);
      }
    }
    // drain stores to coherence point; publish flag. NO cache writeback ops.
    asm volatile("s_waitcnt vmcnt(0)" ::: "memory");
    __syncthreads();
    if (tid == 0)
      __hip_atomic_store(flags + (size_t)t * 256 + wg, 1u,
                         __ATOMIC_RELAXED, __HIP_MEMORY_SCOPE_AGENT);
    // ---- off-critical-path writes (after flag) ----
    if (chunk == 1) {                     // outputs
      float* od = out + (size_t)t * 65536 + (size_t)orow * 1024 + hcol;
      #pragma unroll
      for (int q = 0; q < 4; q++)
        __builtin_nontemporal_store(hq[q], od + (size_t)q * 1024);
    }
    if (t == T_STEPS - 1) {
      if (chunk == 2) {                   // hT
        #pragma unroll
        for (int q = 0; q < 4; q++)
          out[16777216 + (size_t)(orow + q) * 1024 + hcol] = hq[q];
      } else if (chunk == 3) {            // cT
        #pragma unroll
        for (int q = 0; q < 4; q++)
          out[16842752 + (size_t)(orow + q) * 1024 + hcol] = c_st[q];
      }
    }
  }
}

extern "C" void kernel_launch(void* const* d_in, const int* in_sizes, int n_in,
                              void* d_out, int out_size, void* d_ws, size_t ws_size,
                              hipStream_t stream) {
  const float* input = (const float*)d_in[0];
  const float* h0    = (const float*)d_in[1];
  const float* c0    = (const float*)d_in[2];
  const float* wmask = (const float*)d_in[3];
  const float* wih   = (const float*)d_in[4];
  const float* whh   = (const float*)d_in[5];
  const float* bih   = (const float*)d_in[6];
  const float* bhh   = (const float*)d_in[7];
  float* out = (float*)d_out;
  char* ws = (char*)d_ws;

  unsigned short* abfh  = (unsigned short*)(ws + ABFH_OFF);
  unsigned short* abfl  = (unsigned short*)(ws + ABFL_OFF);
  unsigned short* wihfh = (unsigned short*)(ws + WIHFH_OFF);
  unsigned short* wihfl = (unsigned short*)(ws + WIHFL_OFF);
  unsigned short* whfh  = (unsigned short*)(ws + WHFH_OFF);
  unsigned short* whfl  = (unsigned short*)(ws + WHFL_OFF);
  float*          bsum  = (float*)(ws + BSUM_OFF);
  unsigned int*   flags = (unsigned int*)(ws + FLAGS_OFF);
  unsigned short* hhh   = (unsigned short*)(ws + HHH_OFF);
  unsigned short* hhl   = (unsigned short*)(ws + HHL_OFF);

  hipLaunchKernelGGL(prep1, dim3(1024), dim3(256), 0, stream,
                     input, bih, bhh, h0, abfh, abfl, bsum, flags, hhh, hhl);
  hipLaunchKernelGGL(prep2, dim3(2048), dim3(256), 0, stream, whh, wmask, whfh, whfl);
  hipLaunchKernelGGL(prep2b, dim3(1024), dim3(256), 0, stream, wih, wihfh, wihfl);
  hipLaunchKernelGGL(lstm_rec, dim3(256), dim3(256), 0, stream,
                     whfh, whfl, wihfh, wihfl, abfh, abfl, c0, bsum, hhh, hhl, flags, out);
}